// Round 1
// baseline (770.751 us; speedup 1.0000x reference)
//
#include <hip/hip_runtime.h>
#include <math.h>

#define SA    8
#define NKEYS 100000
#define NP    100096      // padded row stride for s_i (391*256)
#define DK    64
#define DA    2048
#define BB    64
#define KMAX  32
static constexpr float EPSF = 1e-8f;

// ---------------- kernel 1: queries[b,s,k] = sum_a W_Q[s,k,a]*z[b,a] ----------------
// grid (16 kg, 8 s), block 256 (4 waves). wave handles k = kg*4+wave, lane = b.
__global__ __launch_bounds__(256) void k_queries(const float* __restrict__ z,
                                                 const float* __restrict__ WQ,
                                                 float* __restrict__ q) {
  __shared__ float zt[64 * 65];
  const int kg = blockIdx.x, s = blockIdx.y;
  const int tid = threadIdx.x;
  const int wave = tid >> 6, lane = tid & 63;
  const int k = kg * 4 + wave;
  const float* wrow = WQ + ((size_t)(s * DK + k)) * DA;
  float acc = 0.f;
  for (int a0 = 0; a0 < DA; a0 += 64) {
    __syncthreads();
#pragma unroll
    for (int r = 0; r < 16; ++r) {
      int i = tid + 256 * r;
      int bl = i >> 6, al = i & 63;
      zt[al * 65 + bl] = z[bl * DA + a0 + al];   // coalesced read, conflict-free write
    }
    __syncthreads();
#pragma unroll
    for (int al = 0; al < 64; al += 4) {
      float4 wq = *(const float4*)(wrow + a0 + al);   // wave-uniform, HW broadcast
      acc = fmaf(wq.x, zt[(al + 0) * 65 + lane], acc);
      acc = fmaf(wq.y, zt[(al + 1) * 65 + lane], acc);
      acc = fmaf(wq.z, zt[(al + 2) * 65 + lane], acc);
      acc = fmaf(wq.w, zt[(al + 3) * 65 + lane], acc);
    }
  }
  q[(lane * SA + s) * DK + k] = acc;   // layout (b*8+s)*64+k
}

// ---------------- kernel 1b: qn = q/(||q||+eps) in place; w = softmax(aw) ----------------
__global__ __launch_bounds__(256) void k_norm_q(float* __restrict__ q,
                                                const float* __restrict__ aw,
                                                float* __restrict__ wbuf) {
  int t = blockIdx.x * 256 + threadIdx.x;   // 0..511 = b*8+s
  if (t < BB * SA) {
    float* row = q + t * DK;
    float ss = 0.f;
#pragma unroll
    for (int c = 0; c < 16; ++c) {
      float4 v = *(const float4*)(row + 4 * c);
      ss += v.x * v.x + v.y * v.y + v.z * v.z + v.w * v.w;
    }
    float inv = 1.f / (sqrtf(ss) + EPSF);
#pragma unroll
    for (int c = 0; c < 16; ++c) {
      float4* p = (float4*)(row + 4 * c);
      float4 v = *p;
      v.x *= inv; v.y *= inv; v.z *= inv; v.w *= inv;
      *p = v;
    }
  }
  if (blockIdx.x == 0 && threadIdx.x == 0) {
    float m = -INFINITY;
    for (int s = 0; s < SA; ++s) m = fmaxf(m, aw[s]);
    float e[SA], sum = 0.f;
    for (int s = 0; s < SA; ++s) { e[s] = __expf(aw[s] - m); sum += e[s]; }
    for (int s = 0; s < SA; ++s) wbuf[s] = e[s] / sum;
  }
}

// ---------------- kernel 2: s_i[b,n] = sum_s (w_s/(||k_sn||+eps)) * qn[b,s,:].k[s,n,:] ----------------
// grid 782 blocks of 128 threads. tile 64b x 128n, microtile 8x8, XOR-swizzled LDS.
__global__ __launch_bounds__(128, 2) void k_sim(const float* __restrict__ pk,
                                                const float* __restrict__ q,
                                                const float* __restrict__ wbuf,
                                                float* __restrict__ si) {
  __shared__ float As[64 * 64];
  __shared__ float Bs[128 * 64];
  const int tid = threadIdx.x;
  const int n0 = blockIdx.x * 128;
  const int tb = tid & 7;    // b-group 0..7
  const int tn = tid >> 3;   // n-group 0..15
  float acc[8][8];
#pragma unroll
  for (int i = 0; i < 8; ++i)
#pragma unroll
    for (int j = 0; j < 8; ++j) acc[i][j] = 0.f;

  for (int s = 0; s < SA; ++s) {
    __syncthreads();
    // stage A (qn): 64x64 = 1024 float4, 8/thread
#pragma unroll
    for (int r = 0; r < 8; ++r) {
      int f = tid + 128 * r;
      int row = f >> 4, cg = f & 15;
      float4 v = *(const float4*)(q + (row * SA + s) * DK + cg * 4);
      *(float4*)(As + row * 64 + ((cg ^ (row & 15)) << 2)) = v;
    }
    // stage B (pool_keys): 128x64 = 2048 float4, 16/thread
#pragma unroll
    for (int r = 0; r < 16; ++r) {
      int f = tid + 128 * r;
      int row = f >> 4, cg = f & 15;
      int n = n0 + row; if (n >= NKEYS) n = NKEYS - 1;
      float4 v = *(const float4*)(pk + ((size_t)s * NKEYS + n) * DK + cg * 4);
      *(float4*)(Bs + row * 64 + ((cg ^ (row & 15)) << 2)) = v;
    }
    __syncthreads();
    // per-row norm, fold w_s * 1/(||k||+eps) into B tile (thread per row)
    {
      int row = tid;
      int swz = row & 15;
      float ss = 0.f;
#pragma unroll
      for (int cg = 0; cg < 16; ++cg) {
        float4 v = *(const float4*)(Bs + row * 64 + ((cg ^ swz) << 2));
        ss += v.x * v.x + v.y * v.y + v.z * v.z + v.w * v.w;
      }
      float sc = wbuf[s] / (sqrtf(ss) + EPSF);
#pragma unroll
      for (int cg = 0; cg < 16; ++cg) {
        float4* p = (float4*)(Bs + row * 64 + ((cg ^ swz) << 2));
        float4 v = *p;
        v.x *= sc; v.y *= sc; v.z *= sc; v.w *= sc;
        *p = v;
      }
    }
    __syncthreads();
    // GEMM 64x128x64
#pragma unroll
    for (int kk = 0; kk < 64; kk += 4) {
      const int k4 = kk >> 2;
      float4 a[8], bfr[8];
#pragma unroll
      for (int i = 0; i < 8; ++i) {
        int row = tb + 8 * i;
        a[i] = *(const float4*)(As + row * 64 + ((k4 ^ (row & 15)) << 2));
      }
#pragma unroll
      for (int h = 0; h < 2; ++h)
#pragma unroll
        for (int qq = 0; qq < 4; ++qq) {
          int row = 4 * tn + qq + 64 * h;
          bfr[h * 4 + qq] = *(const float4*)(Bs + row * 64 + ((k4 ^ (row & 15)) << 2));
        }
#pragma unroll
      for (int i = 0; i < 8; ++i)
#pragma unroll
        for (int j = 0; j < 8; ++j) {
          acc[i][j] = fmaf(a[i].x, bfr[j].x, acc[i][j]);
          acc[i][j] = fmaf(a[i].y, bfr[j].y, acc[i][j]);
          acc[i][j] = fmaf(a[i].z, bfr[j].z, acc[i][j]);
          acc[i][j] = fmaf(a[i].w, bfr[j].w, acc[i][j]);
        }
    }
  }
  // epilogue: n = n0 + 64h + 4tn + qq (float4-contiguous)
#pragma unroll
  for (int i = 0; i < 8; ++i) {
    int bidx = tb + 8 * i;
#pragma unroll
    for (int h = 0; h < 2; ++h) {
      int n = n0 + 64 * h + 4 * tn;
      if (n < NKEYS) {   // N%4==0, n%4==0 -> whole float4 in/out
        float4 v = make_float4(acc[i][h * 4 + 0], acc[i][h * 4 + 1],
                               acc[i][h * 4 + 2], acc[i][h * 4 + 3]);
        *(float4*)(si + (size_t)bidx * NP + n) = v;
      }
    }
  }
}

// ---------------- kernel 3: per-b top-32 + R=sum g*exp(s) + alpha epilogue ----------------
// grid 64 blocks (one per b) of 256 threads (4 waves).
__global__ __launch_bounds__(256) void k_topk(const float* __restrict__ si,
                                              const float* __restrict__ lam_p,
                                              const float* __restrict__ tau_p,
                                              const int* __restrict__ warm_p,
                                              float* __restrict__ out) {
  const int b = blockIdx.x;
  const int tid = threadIdx.x, wave = tid >> 6, lane = tid & 63;
  const float lam = lam_p[0], tau = tau_p[0];
  const int warm = warm_p[0];
  const float* row = si + (size_t)b * NP;

  float cv = -INFINITY; int ci = 0;   // lane-held sorted-desc 64-list
  float r = 0.f;
  float thr = -INFINITY;              // current rank-31 value (lane 31)

  for (int c = wave; c < 391; c += 4) {
    const int n0 = c * 256;
    float4 v4 = *(const float4*)(row + n0 + lane * 4);   // in-bounds via NP padding
#pragma unroll
    for (int e = 0; e < 4; ++e) {
      float x = (e == 0) ? v4.x : (e == 1) ? v4.y : (e == 2) ? v4.z : v4.w;
      int n = n0 + lane * 4 + e;
      bool valid = n < NKEYS;
      if (valid) {
        float g = 1.f / (1.f + __expf(-lam * (x - tau)));
        r += g * __expf(x);
      }
      unsigned long long m = __ballot(valid && (x > thr));
      while (m) {
        int src = __ffsll((unsigned long long)m) - 1;
        m &= m - 1;
        float xv = __shfl(x, src);
        int xi = n0 + src * 4 + e;
        bool bigger = (cv > xv) || (cv == xv && ci < xi);
        unsigned long long bm = __ballot(bigger);
        int pos = __popcll(bm);                 // insert position (<=31)
        float sv = __shfl_up(cv, 1);
        int sidx = __shfl_up(ci, 1);
        if (lane == pos)      { cv = xv; ci = xi; }
        else if (lane > pos)  { cv = sv; ci = sidx; }
        thr = __shfl(cv, 31);
      }
    }
  }
  // reduce r across wave
#pragma unroll
  for (int o = 32; o; o >>= 1) r += __shfl_xor(r, o);

  __shared__ float lv[4][64];
  __shared__ int   li[4][64];
  __shared__ float lr[4];
  lv[wave][lane] = cv; li[wave][lane] = ci;
  if (lane == 0) lr[wave] = r;
  __syncthreads();

  if (wave == 0) {
    float R = lr[0] + lr[1] + lr[2] + lr[3];
    for (int w = 1; w < 4; ++w) {
      float nv = lv[w][lane]; int ni = li[w][lane];
      float rv = __shfl_xor(nv, 63); int ri = __shfl_xor(ni, 63);   // reverse
      bool take = (rv > cv) || (rv == cv && ri < ci);
      if (take) { cv = rv; ci = ri; }                               // bitonic top-64
#pragma unroll
      for (int j = 32; j; j >>= 1) {                                // clean to desc
        float ov = __shfl_xor(cv, j); int oi = __shfl_xor(ci, j);
        bool lower = (lane & j) == 0;
        bool ob = (ov > cv) || (ov == cv && oi < ci);
        if (ob == lower) { cv = ov; ci = oi; }
      }
    }
    // epilogue: lanes 0..31 hold exact top-32 sorted desc (ties: lowest idx first)
    float t = 0.f;
    if (warm) {
      float mm = __shfl(cv, 0);
      if (lane < KMAX) t = __expf(cv - mm);          // TEMP = 1
      float ssum = t;
#pragma unroll
      for (int o = 32; o; o >>= 1) ssum += __shfl_xor(ssum, o);
      if (lane < KMAX) {
        out[b * KMAX + lane] = t / ssum;
        out[BB * KMAX + b * KMAX + lane] = (float)ci;
      }
    } else {
      if (lane < KMAX) {
        float g = 1.f / (1.f + __expf(-lam * (cv - tau)));
        t = g * __expf(cv) / (R + EPSF);
      }
      float ssum = t;
#pragma unroll
      for (int o = 32; o; o >>= 1) ssum += __shfl_xor(ssum, o);
      if (lane < KMAX) {
        out[b * KMAX + lane] = t / (ssum + EPSF);
        out[BB * KMAX + b * KMAX + lane] = (float)ci;
      }
    }
  }
}

extern "C" void kernel_launch(void* const* d_in, const int* in_sizes, int n_in,
                              void* d_out, int out_size, void* d_ws, size_t ws_size,
                              hipStream_t stream) {
  const float* z   = (const float*)d_in[0];
  const float* pk  = (const float*)d_in[1];
  const float* WQ  = (const float*)d_in[2];
  const float* aw  = (const float*)d_in[3];
  const float* tau = (const float*)d_in[4];
  const float* lam = (const float*)d_in[5];
  const int* warm  = (const int*)d_in[6];
  float* out = (float*)d_out;

  float* w  = (float*)d_ws;
  float* qn = w;                 // 512*64 floats (queries, normalized in place)
  float* wb = w + 32768;         // 8 floats (softmax weights)
  float* si = w + 65536;         // 64 * NP floats (s_i, padded rows)

  k_queries<<<dim3(16, SA), 256, 0, stream>>>(z, WQ, qn);
  k_norm_q<<<dim3(2), 256, 0, stream>>>(qn, aw, wb);
  k_sim<<<dim3((NKEYS + 127) / 128), 128, 0, stream>>>(pk, qn, wb, si);
  k_topk<<<dim3(BB), 256, 0, stream>>>(si, lam, tau, warm, out);
}

// Round 2
// 565.636 us; speedup vs baseline: 1.3626x; 1.3626x over previous
//
#include <hip/hip_runtime.h>
#include <math.h>

#define SA    8
#define NKEYS 100000
#define NP    100096      // padded row stride for s_i (391*256)
#define DK    64
#define DA    2048
#define BB    64
#define KMAX  32
static constexpr float EPSF = 1e-8f;

// ---------------- kernel 1: queries[b,s,k] = sum_a W_Q[s,k,a]*z[b,a] ----------------
// barrier-free: one wave per (s,k), lane = b. 256 blocks x 128 threads.
__global__ __launch_bounds__(128) void k_queries(const float* __restrict__ z,
                                                 const float* __restrict__ WQ,
                                                 float* __restrict__ q) {
  const int w = blockIdx.x * 2 + (threadIdx.x >> 6);   // 0..511 = s*64+k
  const int s = w >> 6, k = w & 63;
  const int lane = threadIdx.x & 63;                   // = b
  const float* wrow = WQ + (size_t)(s * DK + k) * DA;
  const float* zrow = z + (size_t)lane * DA;
  float acc = 0.f;
#pragma unroll 8
  for (int a0 = 0; a0 < DA; a0 += 4) {
    float4 wq = *(const float4*)(wrow + a0);   // wave-uniform -> HW broadcast
    float4 zv = *(const float4*)(zrow + a0);   // L1-line reuse across iters
    acc = fmaf(wq.x, zv.x, acc);
    acc = fmaf(wq.y, zv.y, acc);
    acc = fmaf(wq.z, zv.z, acc);
    acc = fmaf(wq.w, zv.w, acc);
  }
  q[(lane * SA + s) * DK + k] = acc;   // layout (b*8+s)*64+k
}

// ---------------- kernel 1b: qn = q/(||q||+eps) in place; w = softmax(aw) ----------------
__global__ __launch_bounds__(256) void k_norm_q(float* __restrict__ q,
                                                const float* __restrict__ aw,
                                                float* __restrict__ wbuf) {
  int t = blockIdx.x * 256 + threadIdx.x;   // 0..511 = b*8+s
  if (t < BB * SA) {
    float* row = q + t * DK;
    float ss = 0.f;
#pragma unroll
    for (int c = 0; c < 16; ++c) {
      float4 v = *(const float4*)(row + 4 * c);
      ss += v.x * v.x + v.y * v.y + v.z * v.z + v.w * v.w;
    }
    float inv = 1.f / (sqrtf(ss) + EPSF);
#pragma unroll
    for (int c = 0; c < 16; ++c) {
      float4* p = (float4*)(row + 4 * c);
      float4 v = *p;
      v.x *= inv; v.y *= inv; v.z *= inv; v.w *= inv;
      *p = v;
    }
  }
  if (blockIdx.x == 0 && threadIdx.x == 0) {
    float m = -INFINITY;
    for (int s = 0; s < SA; ++s) m = fmaxf(m, aw[s]);
    float e[SA], sum = 0.f;
    for (int s = 0; s < SA; ++s) { e[s] = __expf(aw[s] - m); sum += e[s]; }
    for (int s = 0; s < SA; ++s) wbuf[s] = e[s] / sum;
  }
}

// ---------------- kernel 2: s_i[b,n] = sum_s (w_s/(||k_sn||+eps)) * qn[b,s,:].k[s,n,:] ----------------
// 782 blocks x 128 threads, tile 64b x 128n, 8x8 microtile.
// Register-prefetched B staging: next s-tile's global loads overlap current GEMM.
// Row norms computed in-register (16-lane shfl reduce) -> no LDS norm pass.
__global__ __launch_bounds__(128) void k_sim(const float* __restrict__ pk,
                                             const float* __restrict__ q,
                                             const float* __restrict__ wbuf,
                                             float* __restrict__ si) {
  __shared__ float As[64 * 64];
  __shared__ float Bs[128 * 64];
  const int tid = threadIdx.x;
  const int n0 = blockIdx.x * 128;
  const int rg  = tid >> 4;    // row subgroup 0..7
  const int c16 = tid & 15;    // float4 column within row
  const int tb = tid & 7;      // b-group 0..7
  const int tn = tid >> 3;     // n-group 0..15

  float acc[8][8];
#pragma unroll
  for (int i = 0; i < 8; ++i)
#pragma unroll
    for (int j = 0; j < 8; ++j) acc[i][j] = 0.f;

  float4 breg[16];
  auto issueB = [&](int s) {
#pragma unroll
    for (int p = 0; p < 16; ++p) {
      int r = p * 8 + rg;
      int n = n0 + r; if (n >= NKEYS) n = NKEYS - 1;
      breg[p] = *(const float4*)(pk + ((size_t)s * NKEYS + n) * 64 + c16 * 4);
    }
  };

  issueB(0);

  for (int s = 0; s < SA; ++s) {
    // A loads (L2-hot, 8 independent) issued before the B-norm math
    float4 areg[8];
#pragma unroll
    for (int p = 0; p < 8; ++p) {
      int r = p * 8 + rg;
      areg[p] = *(const float4*)(q + (r * SA + s) * DK + c16 * 4);
    }
    const float wsc = wbuf[s];
    // row sums of squares: dot own float4, reduce across the row's 16 lanes
    float ssr[16];
#pragma unroll
    for (int p = 0; p < 16; ++p) {
      float4 v = breg[p];
      float d = v.x * v.x + v.y * v.y + v.z * v.z + v.w * v.w;
      d += __shfl_xor(d, 1); d += __shfl_xor(d, 2);
      d += __shfl_xor(d, 4); d += __shfl_xor(d, 8);
      ssr[p] = d;
    }
    // scale and write B to LDS (swizzled)
#pragma unroll
    for (int p = 0; p < 16; ++p) {
      int r = p * 8 + rg;
      float sc = wsc / (sqrtf(ssr[p]) + EPSF);
      float4 v = breg[p];
      v.x *= sc; v.y *= sc; v.z *= sc; v.w *= sc;
      *(float4*)(Bs + r * 64 + ((c16 ^ (r & 15)) << 2)) = v;
    }
    // write A to LDS (swizzled)
#pragma unroll
    for (int p = 0; p < 8; ++p) {
      int r = p * 8 + rg;
      *(float4*)(As + r * 64 + ((c16 ^ (r & 15)) << 2)) = areg[p];
    }
    __syncthreads();
    // prefetch next s-tile: these loads fly during the GEMM below
    if (s < SA - 1) issueB(s + 1);
    // GEMM 64x128x64 from LDS
#pragma unroll
    for (int k4 = 0; k4 < 16; ++k4) {
      float4 a[8];
#pragma unroll
      for (int i = 0; i < 8; ++i) {
        int r = tb + 8 * i;
        a[i] = *(const float4*)(As + r * 64 + ((k4 ^ (r & 15)) << 2));
      }
#pragma unroll
      for (int j = 0; j < 8; ++j) {
        int r = 4 * tn + (j & 3) + 64 * (j >> 2);
        float4 bv = *(const float4*)(Bs + r * 64 + ((k4 ^ (r & 15)) << 2));
#pragma unroll
        for (int i = 0; i < 8; ++i) {
          acc[i][j] = fmaf(a[i].x, bv.x, acc[i][j]);
          acc[i][j] = fmaf(a[i].y, bv.y, acc[i][j]);
          acc[i][j] = fmaf(a[i].z, bv.z, acc[i][j]);
          acc[i][j] = fmaf(a[i].w, bv.w, acc[i][j]);
        }
      }
    }
    __syncthreads();
  }
  // epilogue: n = n0 + 64h + 4tn + qq (float4-contiguous, 64B-aligned lines)
#pragma unroll
  for (int i = 0; i < 8; ++i) {
    int bidx = tb + 8 * i;
#pragma unroll
    for (int h = 0; h < 2; ++h) {
      int n = n0 + 64 * h + 4 * tn;
      if (n < NKEYS) {
        float4 v = make_float4(acc[i][h * 4 + 0], acc[i][h * 4 + 1],
                               acc[i][h * 4 + 2], acc[i][h * 4 + 3]);
        *(float4*)(si + (size_t)bidx * NP + n) = v;
      }
    }
  }
}

// ---------------- kernel 3: per-b top-32 + R=sum g*exp(s) + alpha epilogue ----------------
// 64 blocks (one per b) x 512 threads (8 waves), depth-2 stream prefetch.
__global__ __launch_bounds__(512) void k_topk(const float* __restrict__ si,
                                              const float* __restrict__ lam_p,
                                              const float* __restrict__ tau_p,
                                              const int* __restrict__ warm_p,
                                              float* __restrict__ out) {
  const int b = blockIdx.x;
  const int tid = threadIdx.x, wave = tid >> 6, lane = tid & 63;
  const float lam = lam_p[0], tau = tau_p[0];
  const int warm = warm_p[0];
  const float* row = si + (size_t)b * NP;

  float cv = -INFINITY; int ci = 0;   // lane-held sorted-desc 64-list
  float r = 0.f;
  float thr = -INFINITY;              // current rank-31 value

  // depth-2 prefetched stream: chunks c = wave, wave+8, ... < 391
  int c = wave;
  float4 f0 = *(const float4*)(row + c * 256 + lane * 4);
  int cn = (c + 8 < 391) ? c + 8 : c;
  float4 f1 = *(const float4*)(row + cn * 256 + lane * 4);
  while (c < 391) {
    const int n0 = c * 256;
    float4 v4 = f0;
    f0 = f1;
    int cp = (c + 16 < 391) ? c + 16 : c;
    f1 = *(const float4*)(row + cp * 256 + lane * 4);
    c += 8;
#pragma unroll
    for (int e = 0; e < 4; ++e) {
      float x = (e == 0) ? v4.x : (e == 1) ? v4.y : (e == 2) ? v4.z : v4.w;
      int n = n0 + lane * 4 + e;
      bool valid = n < NKEYS;
      if (valid) {
        float g = 1.f / (1.f + __expf(-lam * (x - tau)));
        r += g * __expf(x);
      }
      unsigned long long m = __ballot(valid && (x > thr));
      while (m) {
        int src = __ffsll((unsigned long long)m) - 1;
        m &= m - 1;
        float xv = __shfl(x, src);
        int xi = n0 + src * 4 + e;
        bool bigger = (cv > xv) || (cv == xv && ci < xi);
        unsigned long long bm = __ballot(bigger);
        int pos = __popcll(bm);
        float sv = __shfl_up(cv, 1);
        int sidx = __shfl_up(ci, 1);
        if (lane == pos)      { cv = xv; ci = xi; }
        else if (lane > pos)  { cv = sv; ci = sidx; }
        thr = __shfl(cv, 31);
      }
    }
  }
  // reduce r across wave
#pragma unroll
  for (int o = 32; o; o >>= 1) r += __shfl_xor(r, o);

  __shared__ float lv[8][64];
  __shared__ int   li[8][64];
  __shared__ float lr[8];
  lv[wave][lane] = cv; li[wave][lane] = ci;
  if (lane == 0) lr[wave] = r;
  __syncthreads();

  if (wave == 0) {
    float R = 0.f;
#pragma unroll
    for (int w = 0; w < 8; ++w) R += lr[w];
    for (int w = 1; w < 8; ++w) {
      float nv = lv[w][lane]; int ni = li[w][lane];
      float rv = __shfl_xor(nv, 63); int ri = __shfl_xor(ni, 63);   // reverse
      bool take = (rv > cv) || (rv == cv && ri < ci);
      if (take) { cv = rv; ci = ri; }                               // bitonic merge
#pragma unroll
      for (int j = 32; j; j >>= 1) {                                // clean to desc
        float ov = __shfl_xor(cv, j); int oi = __shfl_xor(ci, j);
        bool lower = (lane & j) == 0;
        bool ob = (ov > cv) || (ov == cv && oi < ci);
        if (ob == lower) { cv = ov; ci = oi; }
      }
    }
    // lanes 0..31 hold exact top-32 sorted desc (ties: lowest idx first)
    float t = 0.f;
    if (warm) {
      float mm = __shfl(cv, 0);
      if (lane < KMAX) t = __expf(cv - mm);          // TEMP = 1
      float ssum = t;
#pragma unroll
      for (int o = 32; o; o >>= 1) ssum += __shfl_xor(ssum, o);
      if (lane < KMAX) {
        out[b * KMAX + lane] = t / ssum;
        out[BB * KMAX + b * KMAX + lane] = (float)ci;
      }
    } else {
      if (lane < KMAX) {
        float g = 1.f / (1.f + __expf(-lam * (cv - tau)));
        t = g * __expf(cv) / (R + EPSF);
      }
      float ssum = t;
#pragma unroll
      for (int o = 32; o; o >>= 1) ssum += __shfl_xor(ssum, o);
      if (lane < KMAX) {
        out[b * KMAX + lane] = t / (ssum + EPSF);
        out[BB * KMAX + b * KMAX + lane] = (float)ci;
      }
    }
  }
}

extern "C" void kernel_launch(void* const* d_in, const int* in_sizes, int n_in,
                              void* d_out, int out_size, void* d_ws, size_t ws_size,
                              hipStream_t stream) {
  const float* z   = (const float*)d_in[0];
  const float* pk  = (const float*)d_in[1];
  const float* WQ  = (const float*)d_in[2];
  const float* aw  = (const float*)d_in[3];
  const float* tau = (const float*)d_in[4];
  const float* lam = (const float*)d_in[5];
  const int* warm  = (const int*)d_in[6];
  float* out = (float*)d_out;

  float* w  = (float*)d_ws;
  float* qn = w;                 // 512*64 floats (queries, normalized in place)
  float* wb = w + 32768;         // 8 floats (softmax weights)
  float* si = w + 65536;         // 64 * NP floats (s_i, padded rows)

  k_queries<<<dim3(256), 128, 0, stream>>>(z, WQ, qn);
  k_norm_q<<<dim3(2), 256, 0, stream>>>(qn, aw, wb);
  k_sim<<<dim3((NKEYS + 127) / 128), 128, 0, stream>>>(pk, qn, wb, si);
  k_topk<<<dim3(BB), 512, 0, stream>>>(si, lam, tau, warm, out);
}

// Round 5
// 373.033 us; speedup vs baseline: 2.0662x; 1.5163x over previous
//
#include <hip/hip_runtime.h>
#include <math.h>

#define SA    8
#define NKEYS 100000
#define NP    100096      // padded row stride for s_i (782*128)
#define DK    64
#define DA    2048
#define BB    64
#define KMAX  32
static constexpr float EPSF = 1e-8f;

typedef short  bf16x8 __attribute__((ext_vector_type(8)));
typedef float  f32x4  __attribute__((ext_vector_type(4)));

// RNE bf16 split: x ~= hi + lo, residual <= 2^-18 |x|
__device__ inline void split2(float x, unsigned short& h, unsigned short& l) {
  unsigned u = __float_as_uint(x);
  unsigned r = u + 0x7FFFu + ((u >> 16) & 1u);
  h = (unsigned short)(r >> 16);
  float hf = __uint_as_float(r & 0xFFFF0000u);
  float lo = x - hf;                    // exact
  unsigned ul = __float_as_uint(lo);
  unsigned rl = ul + 0x7FFFu + ((ul >> 16) & 1u);
  l = (unsigned short)(rl >> 16);
}

// ---------------- kernel 1: queries[b,s,k] = sum_a W_Q[s,k,a]*z[b,a] ----------------
// one wave per (b,s,k) dot of length 2048; fully coalesced.
__global__ __launch_bounds__(256) void k_queries(const float* __restrict__ z,
                                                 const float* __restrict__ WQ,
                                                 float* __restrict__ q) {
  const int t = blockIdx.x * 4 + (threadIdx.x >> 6);   // 0..32767 = b*512 + s*64 + k
  const int lane = threadIdx.x & 63;
  const int b = t >> 9, sk = t & 511;
  const float4* w4 = (const float4*)WQ + (size_t)sk * 512;
  const float4* z4 = (const float4*)z + (size_t)b * 512;
  float acc = 0.f;
#pragma unroll
  for (int i = 0; i < 8; ++i) {
    float4 a = w4[lane + 64 * i];
    float4 c = z4[lane + 64 * i];
    acc = fmaf(a.x, c.x, fmaf(a.y, c.y, fmaf(a.z, c.z, fmaf(a.w, c.w, acc))));
  }
#pragma unroll
  for (int o = 32; o; o >>= 1) acc += __shfl_xor(acc, o);
  if (lane == 0) q[(b * SA + (sk >> 6)) * DK + (sk & 63)] = acc;
}

// ---------------- kernel 1b: normalize q rows, split to bf16 hi/lo [s][b][k]; softmax(aw) ----------------
__global__ __launch_bounds__(256) void k_norm(const float* __restrict__ q,
                                              const float* __restrict__ aw,
                                              unsigned short* __restrict__ qh,
                                              unsigned short* __restrict__ ql,
                                              float* __restrict__ wbuf) {
  const int t = blockIdx.x * 4 + (threadIdx.x >> 6);   // 0..511 = b*8+s
  const int lane = threadIdx.x & 63;
  float x = q[t * DK + lane];
  float ss = x * x;
#pragma unroll
  for (int o = 32; o; o >>= 1) ss += __shfl_xor(ss, o);
  float xn = x / (sqrtf(ss) + EPSF);
  unsigned short h, l;
  split2(xn, h, l);
  const int b = t >> 3, s = t & 7;
  const int o = (s * BB + b) * DK + lane;
  qh[o] = h; ql[o] = l;
  if (blockIdx.x == 0 && threadIdx.x == 0) {
    float m = -INFINITY;
    for (int s2 = 0; s2 < SA; ++s2) m = fmaxf(m, aw[s2]);
    float e[SA], sum = 0.f;
    for (int s2 = 0; s2 < SA; ++s2) { e[s2] = __expf(aw[s2] - m); sum += e[s2]; }
    for (int s2 = 0; s2 < SA; ++s2) wbuf[s2] = e[s2] / sum;
  }
}

// ---------------- kernel 2: s_i via 4-pass split-bf16 MFMA ----------------
// 782 blocks x 256 thr (4 waves). Block tile 64b x 128n; wave = 64b x 32n.
// LDS 48 KB -> 3 blocks/CU. Register-prefetch next s-tile during MFMA.
__global__ __launch_bounds__(256, 3) void k_sim(const float* __restrict__ pk,
                                                const unsigned short* __restrict__ qh,
                                                const unsigned short* __restrict__ ql,
                                                const float* __restrict__ wbuf,
                                                float* __restrict__ si) {
  __shared__ unsigned short Ah[64 * 64], Al[64 * 64];     // 8 KB each
  __shared__ unsigned short Bh[128 * 64], Bl[128 * 64];   // 16 KB each
  const int tid = threadIdx.x;
  const int wave = tid >> 6, lane = tid & 63;
  const int n0 = blockIdx.x * 128;
  const int c16 = tid & 15;          // float4 column within row
  const int rg  = tid >> 4;          // 0..15 row group
  const int lm = lane & 15, lq = lane >> 4;
  const int wn0 = wave * 32;

  f32x4 acc[4][2];
#pragma unroll
  for (int mi = 0; mi < 4; ++mi)
#pragma unroll
    for (int ni = 0; ni < 2; ++ni) acc[mi][ni] = (f32x4){0.f, 0.f, 0.f, 0.f};

  float4 breg[8];
  auto issueB = [&](int s) {
#pragma unroll
    for (int p = 0; p < 8; ++p) {
      int n = n0 + rg + 16 * p; if (n >= NKEYS) n = NKEYS - 1;
      breg[p] = *(const float4*)(pk + ((size_t)s * NKEYS + n) * DK + c16 * 4);
    }
  };
  issueB(0);

  for (int s = 0; s < SA; ++s) {
    // A staging regs (qh/ql are tiny & L2-hot)
    ushort4 arh[4], arl[4];
#pragma unroll
    for (int p = 0; p < 4; ++p) {
      int r = rg + 16 * p;
      int o = (s * BB + r) * DK + c16 * 4;
      arh[p] = *(const ushort4*)(qh + o);
      arl[p] = *(const ushort4*)(ql + o);
    }
    const float wsc = wbuf[s];
    // per-row ||k||^2: partial dot + reduce over the 16 lanes sharing the row
    float ssr[8];
#pragma unroll
    for (int p = 0; p < 8; ++p) {
      float4 v = breg[p];
      float d = v.x * v.x + v.y * v.y + v.z * v.z + v.w * v.w;
      d += __shfl_xor(d, 1); d += __shfl_xor(d, 2);
      d += __shfl_xor(d, 4); d += __shfl_xor(d, 8);
      ssr[p] = d;
    }
    // scale, split, write B tiles (swizzled 16B chunks, 8B granular writes)
#pragma unroll
    for (int p = 0; p < 8; ++p) {
      int r = rg + 16 * p;
      float sc = wsc / (sqrtf(ssr[p]) + EPSF);
      float4 v = breg[p];
      v.x *= sc; v.y *= sc; v.z *= sc; v.w *= sc;
      ushort4 hv, lv;
      split2(v.x, hv.x, lv.x); split2(v.y, hv.y, lv.y);
      split2(v.z, hv.z, lv.z); split2(v.w, hv.w, lv.w);
      int widx = r * 64 + (((c16 >> 1) ^ (r & 7)) << 3) + ((c16 & 1) << 2);
      *(ushort4*)(Bh + widx) = hv;
      *(ushort4*)(Bl + widx) = lv;
    }
    // write A tiles
#pragma unroll
    for (int p = 0; p < 4; ++p) {
      int r = rg + 16 * p;
      int widx = r * 64 + (((c16 >> 1) ^ (r & 7)) << 3) + ((c16 & 1) << 2);
      *(ushort4*)(Ah + widx) = arh[p];
      *(ushort4*)(Al + widx) = arl[p];
    }
    __syncthreads();
    if (s < SA - 1) issueB(s + 1);   // flies during MFMA below
    // MFMA: K=64 as 2 steps of 16x16x32; 4 split passes
#pragma unroll
    for (int kk = 0; kk < 2; ++kk) {
      const int chp = (((kk * 4 + lq) ^ (lm & 7)) << 3);
      bf16x8 ah[4], al2[4], bh2[2], bl2[2];
#pragma unroll
      for (int mi = 0; mi < 4; ++mi) {
        int off = (mi * 16 + lm) * 64 + chp;
        ah[mi]  = *(const bf16x8*)(Ah + off);
        al2[mi] = *(const bf16x8*)(Al + off);
      }
#pragma unroll
      for (int ni = 0; ni < 2; ++ni) {
        int off = (wn0 + ni * 16 + lm) * 64 + chp;
        bh2[ni] = *(const bf16x8*)(Bh + off);
        bl2[ni] = *(const bf16x8*)(Bl + off);
      }
#pragma unroll
      for (int mi = 0; mi < 4; ++mi)
#pragma unroll
        for (int ni = 0; ni < 2; ++ni) {
          acc[mi][ni] = __builtin_amdgcn_mfma_f32_16x16x32_bf16(ah[mi],  bh2[ni], acc[mi][ni], 0, 0, 0);
          acc[mi][ni] = __builtin_amdgcn_mfma_f32_16x16x32_bf16(ah[mi],  bl2[ni], acc[mi][ni], 0, 0, 0);
          acc[mi][ni] = __builtin_amdgcn_mfma_f32_16x16x32_bf16(al2[mi], bh2[ni], acc[mi][ni], 0, 0, 0);
          acc[mi][ni] = __builtin_amdgcn_mfma_f32_16x16x32_bf16(al2[mi], bl2[ni], acc[mi][ni], 0, 0, 0);
        }
    }
    __syncthreads();
  }
  // epilogue: C/D layout col=lane&15 (n), row=(lane>>4)*4+reg (b)
#pragma unroll
  for (int mi = 0; mi < 4; ++mi)
#pragma unroll
    for (int ni = 0; ni < 2; ++ni) {
      int n = n0 + wn0 + ni * 16 + lm;
      if (n < NKEYS) {
#pragma unroll
        for (int r = 0; r < 4; ++r) {
          int m = mi * 16 + lq * 4 + r;
          si[(size_t)m * NP + n] = acc[mi][ni][r];
        }
      }
    }
}

// ---------------- kernel 3a: per-(b,slice) top-32 + partial R ----------------
// 512 blocks (b*8+slice) x 256 thr (4 waves); chunks c = sl + 8*wv + 32j.
__global__ __launch_bounds__(256) void k_topk_a(const float* __restrict__ si,
                                                const float* __restrict__ lam_p,
                                                const float* __restrict__ tau_p,
                                                float* __restrict__ candv,
                                                int* __restrict__ candi,
                                                float* __restrict__ Rp) {
  const int b = blockIdx.x >> 3, sl = blockIdx.x & 7;
  const int tid = threadIdx.x, wave = tid >> 6, lane = tid & 63;
  const float lam = lam_p[0], tau = tau_p[0];
  const float* row = si + (size_t)b * NP;

  float cv = -INFINITY; int ci = 0;
  float r = 0.f;
  float thr = -INFINITY;

  int c = sl + 8 * wave;
  float4 f0 = *(const float4*)(row + c * 256 + lane * 4);
  int cn = (c + 32 < 391) ? c + 32 : c;
  float4 f1 = *(const float4*)(row + cn * 256 + lane * 4);
  while (c < 391) {
    const int n0 = c * 256;
    float4 v4 = f0;
    f0 = f1;
    int cp = (c + 64 < 391) ? c + 64 : c;
    f1 = *(const float4*)(row + cp * 256 + lane * 4);
    c += 32;
#pragma unroll
    for (int e = 0; e < 4; ++e) {
      float x = (e == 0) ? v4.x : (e == 1) ? v4.y : (e == 2) ? v4.z : v4.w;
      int n = n0 + lane * 4 + e;
      bool valid = n < NKEYS;
      if (valid) {
        float g = 1.f / (1.f + __expf(-lam * (x - tau)));
        r += g * __expf(x);
      }
      unsigned long long m = __ballot(valid && (x > thr));
      while (m) {
        int src = __ffsll((unsigned long long)m) - 1;
        m &= m - 1;
        float xv = __shfl(x, src);
        int xi = n0 + src * 4 + e;
        bool bigger = (cv > xv) || (cv == xv && ci < xi);
        unsigned long long bm = __ballot(bigger);
        int pos = __popcll(bm);
        float sv = __shfl_up(cv, 1);
        int sidx = __shfl_up(ci, 1);
        if (lane == pos)      { cv = xv; ci = xi; }
        else if (lane > pos)  { cv = sv; ci = sidx; }
        thr = __shfl(cv, 31);
      }
    }
  }
#pragma unroll
  for (int o = 32; o; o >>= 1) r += __shfl_xor(r, o);

  __shared__ float lv[4][64];
  __shared__ int   li[4][64];
  __shared__ float lr[4];
  lv[wave][lane] = cv; li[wave][lane] = ci;
  if (lane == 0) lr[wave] = r;
  __syncthreads();

  if (wave == 0) {
    float R = lr[0] + lr[1] + lr[2] + lr[3];
    for (int w = 1; w < 4; ++w) {
      float nv = lv[w][lane]; int ni = li[w][lane];
      float rv = __shfl_xor(nv, 63); int ri = __shfl_xor(ni, 63);
      bool take = (rv > cv) || (rv == cv && ri < ci);
      if (take) { cv = rv; ci = ri; }
#pragma unroll
      for (int j = 32; j; j >>= 1) {
        float ov = __shfl_xor(cv, j); int oi = __shfl_xor(ci, j);
        bool lower = (lane & j) == 0;
        bool ob = (ov > cv) || (ov == cv && oi < ci);
        if (ob == lower) { cv = ov; ci = oi; }
      }
    }
    if (lane < KMAX) {
      candv[(b * 8 + sl) * KMAX + lane] = cv;
      candi[(b * 8 + sl) * KMAX + lane] = ci;
    }
    if (lane == 0) Rp[b * 8 + sl] = R;
  }
}

// ---------------- kernel 3b: merge 8 sorted top-32 lists per b + epilogue ----------------
__global__ __launch_bounds__(64) void k_topk_b(const float* __restrict__ candv,
                                               const int* __restrict__ candi,
                                               const float* __restrict__ Rp,
                                               const float* __restrict__ lam_p,
                                               const float* __restrict__ tau_p,
                                               const int* __restrict__ warm_p,
                                               float* __restrict__ out) {
  const int b = blockIdx.x, lane = threadIdx.x;
  const float lam = lam_p[0], tau = tau_p[0];
  const int warm = warm_p[0];

  float R = 0.f;
#pragma unroll
  for (int sl = 0; sl < 8; ++sl) R += Rp[b * 8 + sl];

  float cv = (lane < KMAX) ? candv[b * 8 * KMAX + lane] : -INFINITY;
  int   ci = (lane < KMAX) ? candi[b * 8 * KMAX + lane] : 0x7FFFFFFF;
  for (int sl = 1; sl < 8; ++sl) {
    float nv = (lane < KMAX) ? candv[(b * 8 + sl) * KMAX + lane] : -INFINITY;
    int   ni = (lane < KMAX) ? candi[(b * 8 + sl) * KMAX + lane] : 0x7FFFFFFF;
    float rv = __shfl_xor(nv, 63); int ri = __shfl_xor(ni, 63);
    bool take = (rv > cv) || (rv == cv && ri < ci);
    if (take) { cv = rv; ci = ri; }
#pragma unroll
    for (int j = 32; j; j >>= 1) {
      float ov = __shfl_xor(cv, j); int oi = __shfl_xor(ci, j);
      bool lower = (lane & j) == 0;
      bool ob = (ov > cv) || (ov == cv && oi < ci);
      if (ob == lower) { cv = ov; ci = oi; }
    }
  }
  float t = 0.f;
  if (warm) {
    float mm = __shfl(cv, 0);
    if (lane < KMAX) t = __expf(cv - mm);
    float ssum = t;
#pragma unroll
    for (int o = 32; o; o >>= 1) ssum += __shfl_xor(ssum, o);
    if (lane < KMAX) {
      out[b * KMAX + lane] = t / ssum;
      out[BB * KMAX + b * KMAX + lane] = (float)ci;
    }
  } else {
    if (lane < KMAX) {
      float g = 1.f / (1.f + __expf(-lam * (cv - tau)));
      t = g * __expf(cv) / (R + EPSF);
    }
    float ssum = t;
#pragma unroll
    for (int o = 32; o; o >>= 1) ssum += __shfl_xor(ssum, o);
    if (lane < KMAX) {
      out[b * KMAX + lane] = t / (ssum + EPSF);
      out[BB * KMAX + b * KMAX + lane] = (float)ci;
    }
  }
}

extern "C" void kernel_launch(void* const* d_in, const int* in_sizes, int n_in,
                              void* d_out, int out_size, void* d_ws, size_t ws_size,
                              hipStream_t stream) {
  const float* z   = (const float*)d_in[0];
  const float* pk  = (const float*)d_in[1];
  const float* WQ  = (const float*)d_in[2];
  const float* aw  = (const float*)d_in[3];
  const float* tau = (const float*)d_in[4];
  const float* lam = (const float*)d_in[5];
  const int* warm  = (const int*)d_in[6];
  float* out = (float*)d_out;

  // workspace layout (float units); sizes verified:
  //   q     [0,     32768)              32768
  //   wbuf  [32768, 32776) pad-> 32832
  //   Rp    [32832, 33344)                512
  //   candv [33344, 49728)              16384 = 64b*8sl*32
  //   candi [49728, 66112)              16384
  //   qh    [66112, 82496)              32768 ushort = 16384 floats
  //   ql    [82496, 98880)              16384 floats
  //   si    [98880, 98880+64*NP)        6406144
  float* w = (float*)d_ws;
  float* q     = w;
  float* wbuf  = w + 32768;
  float* Rp    = w + 32832;
  float* candv = w + 33344;
  int*   candi = (int*)(w + 49728);
  unsigned short* qh = (unsigned short*)(w + 66112);
  unsigned short* ql = (unsigned short*)(w + 82496);
  float* si    = w + 98880;

  k_queries<<<dim3(8192), 256, 0, stream>>>(z, WQ, q);
  k_norm<<<dim3(128), 256, 0, stream>>>(q, aw, qh, ql, wbuf);
  k_sim<<<dim3((NKEYS + 127) / 128), 256, 0, stream>>>(pk, qh, ql, wbuf, si);
  k_topk_a<<<dim3(512), 256, 0, stream>>>(si, lam, tau, candv, candi, Rp);
  k_topk_b<<<dim3(BB), 64, 0, stream>>>(candv, candi, Rp, lam, tau, warm, out);
}